// Round 1
// baseline (40.062 us; speedup 1.0000x reference)
//
#include <hip/hip_runtime.h>

// TwoBodySplineScalarEmbed: out[e,c] = sum_b basis(x[e])_b * coeffs[cls[e], b, c]
// Quadratic uniform B-spline on [0,1], grid=5, NUM_BASIS=6, only 3 weights nonzero.
constexpr int NUM_TYPES   = 4;
constexpr int NUM_BASIS   = 6;
constexpr int CHANNELS    = 64;
constexpr int COEFF_FLOATS = NUM_TYPES * NUM_TYPES * NUM_BASIS * CHANNELS; // 6144 (24 KiB)

__global__ __launch_bounds__(256)
void TwoBodySplineScalarEmbed_kernel(const float* __restrict__ x,
                                     const int*   __restrict__ edge_types,
                                     const float* __restrict__ coeffs,
                                     float*       __restrict__ out,
                                     int E)
{
    __shared__ float sc[COEFF_FLOATS];
    // Cooperative stage of the (tiny) coefficient table into LDS.
    for (int i = threadIdx.x; i < COEFF_FLOATS; i += blockDim.x)
        sc[i] = coeffs[i];
    __syncthreads();

    const int laneC    = threadIdx.x & 15;   // which float4 of the 64 channels
    const int edgeSub  = threadIdx.x >> 4;   // 0..15: edge within the block tile
    const int edgesPerBlock = blockDim.x >> 4; // 16
    const int c0 = laneC * 4;

    for (int e = blockIdx.x * edgesPerBlock + edgeSub; e < E;
         e += gridDim.x * edgesPerBlock)
    {
        float xv = x[e];
        xv = fminf(fmaxf(xv, 0.0f), 1.0f - 1e-6f);
        float s = xv * 4.0f;               // h = 1/4
        int i0 = (int)s;
        i0 = i0 > 3 ? 3 : i0;              // interval 0..3
        float u = s - (float)i0;           // local coord in [0,1)
        float omu = 1.0f - u;
        float w0 = 0.5f * omu * omu;
        float w1 = u * omu + 0.5f;         // -u^2 + u + 1/2
        float w2 = 0.5f * u * u;

        int cls = edge_types[e] * NUM_TYPES + edge_types[E + e];

        const float* base = &sc[(cls * NUM_BASIS + i0) * CHANNELS + c0];
        float4 r0 = *reinterpret_cast<const float4*>(base);
        float4 r1 = *reinterpret_cast<const float4*>(base + CHANNELS);
        float4 r2 = *reinterpret_cast<const float4*>(base + 2 * CHANNELS);

        float4 o;
        o.x = w0 * r0.x + w1 * r1.x + w2 * r2.x;
        o.y = w0 * r0.y + w1 * r1.y + w2 * r2.y;
        o.z = w0 * r0.z + w1 * r1.z + w2 * r2.z;
        o.w = w0 * r0.w + w1 * r1.w + w2 * r2.w;

        *reinterpret_cast<float4*>(&out[e * CHANNELS + c0]) = o;
    }
}

extern "C" void kernel_launch(void* const* d_in, const int* in_sizes, int n_in,
                              void* d_out, int out_size, void* d_ws, size_t ws_size,
                              hipStream_t stream)
{
    const float* x          = (const float*)d_in[0];
    const int*   edge_types = (const int*)d_in[1];
    const float* coeffs     = (const float*)d_in[2];
    float*       out        = (float*)d_out;

    const int E = in_sizes[0];

    const int block = 256;
    const int edgesPerBlock = block / 16;          // 16
    int grid = (E + edgesPerBlock - 1) / edgesPerBlock;
    if (grid > 2048) grid = 2048;                  // grid-stride; amortize LDS stage

    TwoBodySplineScalarEmbed_kernel<<<grid, block, 0, stream>>>(
        x, edge_types, coeffs, out, E);
}

// Round 2
// 28.604 us; speedup vs baseline: 1.4006x; 1.4006x over previous
//
#include <hip/hip_runtime.h>

// TwoBodySplineScalarEmbed: out[e,c] = sum_b basis(x[e])_b * coeffs[cls[e], b, c]
// Quadratic uniform B-spline on [0,1], grid=5, NUM_BASIS=6; only 3 weights nonzero:
//   i0 = clamp(floor(4x),0,3), u = 4x-i0
//   w0 = (1-u)^2/2, w1 = -u^2+u+1/2, w2 = u^2/2   at basis rows i0..i0+2
constexpr int NUM_TYPES    = 4;
constexpr int NUM_BASIS    = 6;
constexpr int CHANNELS     = 64;
constexpr int COEFF_FLOATS = NUM_TYPES * NUM_TYPES * NUM_BASIS * CHANNELS; // 6144 (24 KiB)

typedef float f4 __attribute__((ext_vector_type(4)));
typedef int   i4 __attribute__((ext_vector_type(4)));

__global__ __launch_bounds__(256)
void TwoBodySplineScalarEmbed_kernel(const float* __restrict__ x,
                                     const int*   __restrict__ edge_types,
                                     const float* __restrict__ coeffs,
                                     float*       __restrict__ out,
                                     int E)
{
    __shared__ float sc[COEFF_FLOATS];
    for (int i = threadIdx.x; i < COEFF_FLOATS; i += 256)
        sc[i] = coeffs[i];
    __syncthreads();

    const int laneC = threadIdx.x & 15;   // which float4 of the 64 channels
    const int grp   = threadIdx.x >> 4;   // 0..15: edge-group within block
    const int c0    = laneC * 4;

    // Each group handles 4 consecutive edges per iteration -> 64 edges/block-iter.
    for (int e0 = blockIdx.x * 64 + grp * 4; e0 < E; e0 += gridDim.x * 64)
    {
        if (e0 + 3 < E) {
            // Vectorized inputs (e0 % 4 == 0, E % 4 == 0 -> 16B aligned)
            f4 xv = *reinterpret_cast<const f4*>(x + e0);
            i4 tc = *reinterpret_cast<const i4*>(edge_types + e0);
            i4 tn = *reinterpret_cast<const i4*>(edge_types + E + e0);

            #pragma unroll
            for (int j = 0; j < 4; ++j) {
                float xj = fminf(fmaxf(xv[j], 0.0f), 1.0f - 1e-6f);
                float s  = xj * 4.0f;
                int   i0 = (int)s;  i0 = i0 > 3 ? 3 : i0;
                float u  = s - (float)i0;
                float omu = 1.0f - u;
                float w0 = 0.5f * omu * omu;
                float w1 = u * omu + 0.5f;
                float w2 = 0.5f * u * u;

                int cls = tc[j] * NUM_TYPES + tn[j];
                const float* base = &sc[(cls * NUM_BASIS + i0) * CHANNELS + c0];
                f4 r0 = *reinterpret_cast<const f4*>(base);
                f4 r1 = *reinterpret_cast<const f4*>(base + CHANNELS);
                f4 r2 = *reinterpret_cast<const f4*>(base + 2 * CHANNELS);

                f4 o = w0 * r0 + w1 * r1 + w2 * r2;
                __builtin_nontemporal_store(
                    o, reinterpret_cast<f4*>(out + (size_t)(e0 + j) * CHANNELS + c0));
            }
        } else {
            // Ragged tail (E not a multiple of 64): scalar-per-edge path.
            for (int j = 0; j < 4; ++j) {
                int e = e0 + j;
                if (e >= E) break;
                float xj = fminf(fmaxf(x[e], 0.0f), 1.0f - 1e-6f);
                float s  = xj * 4.0f;
                int   i0 = (int)s;  i0 = i0 > 3 ? 3 : i0;
                float u  = s - (float)i0;
                float omu = 1.0f - u;
                float w0 = 0.5f * omu * omu;
                float w1 = u * omu + 0.5f;
                float w2 = 0.5f * u * u;

                int cls = edge_types[e] * NUM_TYPES + edge_types[E + e];
                const float* base = &sc[(cls * NUM_BASIS + i0) * CHANNELS + c0];
                f4 r0 = *reinterpret_cast<const f4*>(base);
                f4 r1 = *reinterpret_cast<const f4*>(base + CHANNELS);
                f4 r2 = *reinterpret_cast<const f4*>(base + 2 * CHANNELS);

                f4 o = w0 * r0 + w1 * r1 + w2 * r2;
                __builtin_nontemporal_store(
                    o, reinterpret_cast<f4*>(out + (size_t)e * CHANNELS + c0));
            }
        }
    }
}

extern "C" void kernel_launch(void* const* d_in, const int* in_sizes, int n_in,
                              void* d_out, int out_size, void* d_ws, size_t ws_size,
                              hipStream_t stream)
{
    const float* x          = (const float*)d_in[0];
    const int*   edge_types = (const int*)d_in[1];
    const float* coeffs     = (const float*)d_in[2];
    float*       out        = (float*)d_out;

    const int E = in_sizes[0];

    // 24 KiB LDS/block -> 6 blocks/CU resident; 256 CU * 6 = 1536 all co-resident.
    int grid = (E + 63) / 64;
    if (grid > 1536) grid = 1536;

    TwoBodySplineScalarEmbed_kernel<<<grid, 256, 0, stream>>>(
        x, edge_types, coeffs, out, E);
}